// Round 3
// baseline (519.345 us; speedup 1.0000x reference)
//
#include <hip/hip_runtime.h>
#include <hip/hip_bf16.h>

// Sizes fixed by the reference
#define HV   128
#define HT   17
#define DIMD 290        // 2*(HV+HT)
#define KP   320        // K padded to 10*32 for mfma 16x16x32
#define LDSP 328        // LDS row pitch (bf16 elems) to break bank aliasing
#define OO   640        // 5*HV
#define RT   64         // rows per block
#define KN   8          // number of types
#define GG   384        // persistent grid size

typedef unsigned short u16;
typedef __attribute__((ext_vector_type(8))) short short8v;
typedef __attribute__((ext_vector_type(4))) float f32x4;

__device__ __forceinline__ u16 f2bf(float x) {
    unsigned u = __float_as_uint(x);
    u = (u + 0x7FFFu + ((u >> 16) & 1u)) >> 16;   // RNE
    return (u16)u;
}
__device__ __forceinline__ float sigf(float x) {
    return __builtin_amdgcn_rcpf(1.0f + __expf(-x));
}
__device__ __forceinline__ float tanhfast(float x) {
    return 1.0f - 2.0f * __builtin_amdgcn_rcpf(1.0f + __expf(2.0f * x));
}

// ws header layout (ints): [0..7] counts, [8..15] scatter cursors,
// [16..24] blkStart prefix (blkStart[8] = total row-blocks)

__global__ void hist_k(const int* __restrict__ pt, int* __restrict__ hdr, int N) {
    __shared__ int c[KN];
    if (threadIdx.x < KN) c[threadIdx.x] = 0;
    __syncthreads();
    int n = blockIdx.x * 256 + threadIdx.x;
    if (n < N) atomicAdd(&c[pt[n]], 1);
    __syncthreads();
    if (threadIdx.x < KN && c[threadIdx.x]) atomicAdd(&hdr[threadIdx.x], c[threadIdx.x]);
}

__global__ void prefix_k(int* __restrict__ hdr) {
    if (threadIdx.x == 0 && blockIdx.x == 0) {
        int acc = 0;
        hdr[16] = 0;
        for (int k = 0; k < KN; ++k) {
            acc += (hdr[k] + RT - 1) / RT;
            hdr[17 + k] = acc;
        }
    }
}

__global__ void scatter_k(const int* __restrict__ pt, int* __restrict__ hdr,
                          int* __restrict__ idxbuf, int N) {
    __shared__ int c[KN], base[KN];
    if (threadIdx.x < KN) c[threadIdx.x] = 0;
    __syncthreads();
    int n = blockIdx.x * 256 + threadIdx.x;
    int k = 0, my = 0;
    if (n < N) { k = pt[n]; my = atomicAdd(&c[k], 1); }
    __syncthreads();
    if (threadIdx.x < KN)
        base[threadIdx.x] = c[threadIdx.x] ? atomicAdd(&hdr[8 + threadIdx.x], c[threadIdx.x]) : 0;
    __syncthreads();
    if (n < N) idxbuf[hdr[16 + k] * RT + base[k] + my] = n;
}

// W (K,O,290) fp32 -> Wbf (K,O,320) bf16 with column permutation:
// x' layout = [h_l 0..128 | h_r 128..256 | t_l 256..273 | t_r 273..290 | 0 pad]
__global__ void wconv_k(const float* __restrict__ W, u16* __restrict__ Wbf) {
    int k = blockIdx.y;
    int idx = blockIdx.x * 256 + threadIdx.x;
    if (idx >= OO * KP) return;
    int o = idx / KP, d = idx % KP;
    int src;
    if (d < 256)      src = (d < 128) ? d : d + 17;
    else if (d < 273) src = d - 128;
    else if (d < 290) src = d;
    else              src = -1;
    float v = (src >= 0) ? W[((size_t)k * OO + o) * DIMD + src] : 0.0f;
    Wbf[((size_t)k * OO + o) * KP + d] = f2bf(v);
}

// Persistent blocks, grid-stride over row-tiles. Per iteration:
//   issue next-tile pool loads (regs) -> MFMA current tile (LDS) ->
//   epilogue -> barrier -> cvt+ds_write next tile -> barrier.
__global__ __launch_bounds__(512, 2)
void gemm_lstm_k(const float* __restrict__ h_pool, const float* __restrict__ c_pool,
                 const float* __restrict__ t_pool, const int* __restrict__ child_idx,
                 const float* __restrict__ bias, const u16* __restrict__ Wbf,
                 const int* __restrict__ hdr, const int* __restrict__ idxbuf,
                 float* __restrict__ out) {
    __shared__ u16 sA[RT * LDSP];
    __shared__ int4 sMeta[2][RT];

    const int ntiles = hdr[24];
    int it = blockIdx.x;
    if (it >= ntiles) return;
    const int G = gridDim.x;

    int hp[7];
    #pragma unroll
    for (int j = 0; j < 7; ++j) hp[j] = hdr[17 + j];

    const int tid = threadIdx.x;
    const int r = tid >> 3, q = tid & 7;

    // ---- stage helpers ----
    auto loadmeta = [&](int tile, int& n, int& l, int& rr) {
        n = idxbuf[tile * RT + r];
        if (n >= 0) { l = child_idx[2 * n]; rr = child_idx[2 * n + 1]; }
        else { l = 0; rr = 0; }
    };

    float4 A0[4], B0[4];
    float T0[3], U0[3];

    auto issue_stage = [&](int n, int l, int rr) {
        if (n < 0) return;
        const float4* hl = (const float4*)(h_pool + (size_t)l * HV);
        const float4* hr = (const float4*)(h_pool + (size_t)rr * HV);
        #pragma unroll
        for (int m = 0; m < 4; ++m) A0[m] = hl[q + 8 * m];
        #pragma unroll
        for (int m = 0; m < 4; ++m) B0[m] = hr[q + 8 * m];
        const float* tl = t_pool + (size_t)l * HT;
        const float* tr = t_pool + (size_t)rr * HT;
        T0[0] = tl[q]; T0[1] = tl[q + 8]; if (q == 0) T0[2] = tl[16];
        U0[0] = tr[q]; U0[1] = tr[q + 8]; if (q == 0) U0[2] = tr[16];
    };

    auto write_stage = [&](int n) {
        u16* row = &sA[r * LDSP];
        ushort4* rw  = (ushort4*)row;          // h_l at 0
        ushort4* rw2 = (ushort4*)(row + 128);  // h_r at 128
        if (n >= 0) {
            #pragma unroll
            for (int m = 0; m < 4; ++m) {
                float4 v = A0[m];
                rw[q + 8 * m] = make_ushort4(f2bf(v.x), f2bf(v.y), f2bf(v.z), f2bf(v.w));
            }
            #pragma unroll
            for (int m = 0; m < 4; ++m) {
                float4 v = B0[m];
                rw2[q + 8 * m] = make_ushort4(f2bf(v.x), f2bf(v.y), f2bf(v.z), f2bf(v.w));
            }
            row[256 + q] = f2bf(T0[0]); row[256 + q + 8] = f2bf(T0[1]);
            row[273 + q] = f2bf(U0[0]); row[273 + q + 8] = f2bf(U0[1]);
            if (q == 0) { row[256 + 16] = f2bf(T0[2]); row[273 + 16] = f2bf(U0[2]); }
        } else {
            ushort4 z = make_ushort4(0, 0, 0, 0);
            #pragma unroll
            for (int m = 0; m < 4; ++m) { rw[q + 8 * m] = z; rw2[q + 8 * m] = z; }
            row[256 + q] = 0; row[256 + q + 8] = 0;
            row[273 + q] = 0; row[273 + q + 8] = 0;
            if (q == 0) { row[256 + 16] = 0; row[273 + 16] = 0; }
        }
    };

    // ---- prolog: stage tile it, preload meta of tile it+G ----
    {
        int n1, l1, rr1;
        loadmeta(it, n1, l1, rr1);
        issue_stage(n1, l1, rr1);
        if (q == 0) sMeta[0][r] = make_int4(n1, l1, rr1, 0);
        // zero the pad columns once (never rewritten)
        u16* row = &sA[r * LDSP];
        for (int j = 290 + q; j < KP; j += 8) row[j] = 0;
        write_stage(n1);
    }
    int cn = -1, cl_ = 0, cr_ = 0;
    if (it + G < ntiles) loadmeta(it + G, cn, cl_, cr_);
    __syncthreads();

    const int wc = tid >> 6, lane = tid & 63;
    const int lo = lane & 15, hi = lane >> 4;
    const u16* ap = &sA[lo * LDSP + hi * 8];
    int p = 0;

    for (; it < ntiles; it += G) {
        const bool hasnext = (it + G < ntiles);
        // 1. issue next tile's pool loads (hide under MFMA+epilogue)
        const int mn = cn, ml = cl_, mrr = cr_;
        if (hasnext) {
            issue_stage(mn, ml, mrr);
            if (q == 0) sMeta[p ^ 1][r] = make_int4(mn, ml, mrr, 0);
        }
        // 2. carry meta for tile it+2G (2-deep chain hides under MFMA)
        if (it + 2 * G < ntiles) loadmeta(it + 2 * G, cn, cl_, cr_);

        // 3. type of current tile
        int k = 0;
        #pragma unroll
        for (int j = 0; j < 7; ++j) k += (it >= hp[j]);
        const u16* __restrict__ wbase = Wbf + (size_t)k * (OO * KP);

        // 4. MFMA
        f32x4 acc[5][4];
        #pragma unroll
        for (int g = 0; g < 5; ++g)
            #pragma unroll
            for (int m = 0; m < 4; ++m)
                acc[g][m] = (f32x4){0.f, 0.f, 0.f, 0.f};

        int wo[5];
        #pragma unroll
        for (int g = 0; g < 5; ++g)
            wo[g] = (g * 128 + wc * 16 + lo) * KP + hi * 8;

        #pragma unroll
        for (int kk = 0; kk < 10; ++kk) {
            const int kb = kk * 32;
            short8v a0 = *(const short8v*)(ap + kb);
            short8v a1 = *(const short8v*)(ap + 16 * LDSP + kb);
            short8v a2 = *(const short8v*)(ap + 32 * LDSP + kb);
            short8v a3 = *(const short8v*)(ap + 48 * LDSP + kb);
            #pragma unroll
            for (int g = 0; g < 5; ++g) {
                short8v bf = *(const short8v*)(wbase + wo[g] + kb);
                acc[g][0] = __builtin_amdgcn_mfma_f32_16x16x32_bf16(a0, bf, acc[g][0], 0, 0, 0);
                acc[g][1] = __builtin_amdgcn_mfma_f32_16x16x32_bf16(a1, bf, acc[g][1], 0, 0, 0);
                acc[g][2] = __builtin_amdgcn_mfma_f32_16x16x32_bf16(a2, bf, acc[g][2], 0, 0, 0);
                acc[g][3] = __builtin_amdgcn_mfma_f32_16x16x32_bf16(a3, bf, acc[g][3], 0, 0, 0);
            }
        }

        // 5. fused LSTM epilogue
        const int hcol = wc * 16 + lo;
        float bb[5];
        #pragma unroll
        for (int g = 0; g < 5; ++g) bb[g] = bias[k * OO + g * 128 + hcol];

        #pragma unroll
        for (int m = 0; m < 4; ++m) {
            #pragma unroll
            for (int jj = 0; jj < 4; ++jj) {
                int rl = m * 16 + hi * 4 + jj;
                int4 mt = sMeta[p][rl];
                if (mt.x < 0) continue;
                float cl = c_pool[(size_t)mt.y * HV + hcol];
                float cr = c_pool[(size_t)mt.z * HV + hcol];
                float gi  = acc[0][m][jj] + bb[0];
                float gfl = acc[1][m][jj] + bb[1];
                float gfr = acc[2][m][jj] + bb[2];
                float gu  = acc[3][m][jj] + bb[3];
                float go  = acc[4][m][jj] + bb[4];
                float cc = sigf(gi) * tanhfast(gu) + sigf(gfl) * cl + sigf(gfr) * cr;
                float hh = sigf(go) * tanhfast(cc);
                float* orow = out + (size_t)mt.x * (2 * HV);
                orow[hcol]      = hh;
                orow[HV + hcol] = cc;
            }
        }

        // 6. swap: consume barrier, overwrite sA with next tile, publish barrier
        __syncthreads();
        if (hasnext) write_stage(mn);
        __syncthreads();
        p ^= 1;
    }
}

extern "C" void kernel_launch(void* const* d_in, const int* in_sizes, int n_in,
                              void* d_out, int out_size, void* d_ws, size_t ws_size,
                              hipStream_t stream) {
    const float* h_pool      = (const float*)d_in[0];
    const float* c_pool      = (const float*)d_in[1];
    const float* t_pool      = (const float*)d_in[2];
    const int*   child_idx   = (const int*)d_in[3];
    const int*   parent_type = (const int*)d_in[4];
    const float* W           = (const float*)d_in[5];
    const float* bias        = (const float*)d_in[6];
    float* out = (float*)d_out;

    const int N = in_sizes[3] / 2;

    char* ws = (char*)d_ws;
    int* hdr    = (int*)ws;
    int* idxbuf = (int*)(ws + 1024);
    const int idx_count = N + KN * RT;
    size_t woff = 1024 + (((size_t)idx_count * 4 + 255) / 256) * 256;
    u16* Wbf = (u16*)(ws + woff);

    hipMemsetAsync(hdr, 0, 1024, stream);
    hipMemsetAsync(idxbuf, 0xFF, (size_t)idx_count * 4, stream);

    int nb = (N + 255) / 256;
    hist_k<<<nb, 256, 0, stream>>>(parent_type, hdr, N);
    prefix_k<<<1, 64, 0, stream>>>(hdr);
    scatter_k<<<nb, 256, 0, stream>>>(parent_type, hdr, idxbuf, N);
    wconv_k<<<dim3((OO * KP + 255) / 256, KN), 256, 0, stream>>>(W, Wbf);

    int maxblk = (N + RT - 1) / RT + KN;
    int grid = maxblk < GG ? maxblk : GG;
    gemm_lstm_k<<<grid, 512, 0, stream>>>(
        h_pool, c_pool, t_pool, child_idx, bias, Wbf, hdr, idxbuf, out);
}

// Round 4
// 431.916 us; speedup vs baseline: 1.2024x; 1.2024x over previous
//
#include <hip/hip_runtime.h>
#include <hip/hip_bf16.h>

// Sizes fixed by the reference
#define HV   128
#define HT   17
#define DIMD 290        // 2*(HV+HT)
#define KP   320        // K padded to 10*32 for mfma 16x16x32
#define OO   640        // 5*HV
#define RT   64         // rows per tile
#define KN   8          // number of types

typedef unsigned short u16;
typedef __attribute__((ext_vector_type(8))) short short8v;
typedef __attribute__((ext_vector_type(4))) float f32x4;

__device__ __forceinline__ u16 f2bf(float x) {
    unsigned u = __float_as_uint(x);
    u = (u + 0x7FFFu + ((u >> 16) & 1u)) >> 16;   // RNE
    return (u16)u;
}
__device__ __forceinline__ float sigf(float x) {
    return __builtin_amdgcn_rcpf(1.0f + __expf(-x));
}
__device__ __forceinline__ float tanhfast(float x) {
    return 1.0f - 2.0f * __builtin_amdgcn_rcpf(1.0f + __expf(2.0f * x));
}
__device__ __forceinline__ void gld16(const void* g, void* l) {
    __builtin_amdgcn_global_load_lds(
        (const __attribute__((address_space(1))) unsigned int*)g,
        (__attribute__((address_space(3))) unsigned int*)l, 16, 0, 0);
}

// ws header layout (ints): [0..7] counts, [8..15] scatter cursors,
// [16..24] blkStart prefix (blkStart[8] = total row-blocks)

__global__ void hist_k(const int* __restrict__ pt, int* __restrict__ hdr, int N) {
    __shared__ int c[KN];
    if (threadIdx.x < KN) c[threadIdx.x] = 0;
    __syncthreads();
    int n = blockIdx.x * 256 + threadIdx.x;
    if (n < N) atomicAdd(&c[pt[n]], 1);
    __syncthreads();
    if (threadIdx.x < KN && c[threadIdx.x]) atomicAdd(&hdr[threadIdx.x], c[threadIdx.x]);
}

__global__ void prefix_k(int* __restrict__ hdr) {
    if (threadIdx.x == 0 && blockIdx.x == 0) {
        int acc = 0;
        hdr[16] = 0;
        for (int k = 0; k < KN; ++k) {
            acc += (hdr[k] + RT - 1) / RT;
            hdr[17 + k] = acc;
        }
    }
}

__global__ void scatter_k(const int* __restrict__ pt, int* __restrict__ hdr,
                          int* __restrict__ idxbuf, int N) {
    __shared__ int c[KN], base[KN];
    if (threadIdx.x < KN) c[threadIdx.x] = 0;
    __syncthreads();
    int n = blockIdx.x * 256 + threadIdx.x;
    int k = 0, my = 0;
    if (n < N) { k = pt[n]; my = atomicAdd(&c[k], 1); }
    __syncthreads();
    if (threadIdx.x < KN)
        base[threadIdx.x] = c[threadIdx.x] ? atomicAdd(&hdr[8 + threadIdx.x], c[threadIdx.x]) : 0;
    __syncthreads();
    if (n < N) idxbuf[hdr[16 + k] * RT + base[k] + my] = n;
}

// W (K,O,290) fp32 -> Wbf (K,O,320) bf16 with column permutation:
// x' layout = [h_l 0..128 | h_r 128..256 | t_l 256..273 | t_r 273..290 | 0 pad]
__global__ void wconv_k(const float* __restrict__ W, u16* __restrict__ Wbf) {
    int k = blockIdx.y;
    int idx = blockIdx.x * 256 + threadIdx.x;
    if (idx >= OO * KP) return;
    int o = idx / KP, d = idx % KP;
    int src;
    if (d < 256)      src = (d < 128) ? d : d + 17;
    else if (d < 273) src = d - 128;
    else if (d < 290) src = d;
    else              src = -1;
    float v = (src >= 0) ? W[((size_t)k * OO + o) * DIMD + src] : 0.0f;
    Wbf[((size_t)k * OO + o) * KP + d] = f2bf(v);
}

// Build dense bf16 X (sorted rows, 320 cols, XOR-swizzled within each row)
// and meta[row] = (node, li, ri, 0). 8 threads per row, streaming, no barriers.
__global__ void __launch_bounds__(512)
buildx_k(const float* __restrict__ h_pool, const float* __restrict__ t_pool,
         const int* __restrict__ child_idx, const int* __restrict__ idxbuf,
         u16* __restrict__ X, int4* __restrict__ meta, int totrows) {
    int row = blockIdx.x * 64 + (threadIdx.x >> 3);
    int q = threadIdx.x & 7;
    if (row >= totrows) return;
    int node = idxbuf[row];
    char* xr = (char*)(X + (size_t)row * KP);
    const int swz = (row & 7) << 4;           // byte-XOR within the row

    if (node >= 0) {
        int li = child_idx[2 * node], ri = child_idx[2 * node + 1];
        if (q == 0) meta[row] = make_int4(node, li, ri, 0);
        const float4* hl = (const float4*)(h_pool + (size_t)li * HV);
        const float4* hr = (const float4*)(h_pool + (size_t)ri * HV);
        #pragma unroll
        for (int m = 0; m < 4; ++m) {
            float4 v = hl[q + 8 * m];
            *(ushort4*)(xr + (((q + 8 * m) * 8) ^ swz)) =
                make_ushort4(f2bf(v.x), f2bf(v.y), f2bf(v.z), f2bf(v.w));
        }
        #pragma unroll
        for (int m = 0; m < 4; ++m) {
            float4 v = hr[q + 8 * m];
            *(ushort4*)(xr + ((256 + (q + 8 * m) * 8) ^ swz)) =
                make_ushort4(f2bf(v.x), f2bf(v.y), f2bf(v.z), f2bf(v.w));
        }
        const float* tl = t_pool + (size_t)li * HT;
        const float* tr = t_pool + (size_t)ri * HT;
        *(u16*)(xr + ((512 + 2 * q) ^ swz))       = f2bf(tl[q]);
        *(u16*)(xr + ((512 + 2 * (q + 8)) ^ swz)) = f2bf(tl[q + 8]);
        *(u16*)(xr + ((546 + 2 * q) ^ swz))       = f2bf(tr[q]);
        *(u16*)(xr + ((546 + 2 * (q + 8)) ^ swz)) = f2bf(tr[q + 8]);
        if (q == 0) {
            *(u16*)(xr + (544 ^ swz)) = f2bf(tl[16]);
            *(u16*)(xr + (578 ^ swz)) = f2bf(tr[16]);
        }
        for (int b = 580 + 2 * q; b < 640; b += 16)
            *(u16*)(xr + (b ^ swz)) = 0;
    } else {
        if (q == 0) meta[row] = make_int4(-1, 0, 0, 0);
        ushort4 z = make_ushort4(0, 0, 0, 0);
        for (int b = q * 8; b < 640; b += 64)
            *(ushort4*)(xr + (b ^ swz)) = z;
    }
}

// Dense GEMM + fused LSTM. One block per 64-row tile, 8 waves, wave = 64r x 16
// h-cols x 5 gates. X staged via global_load_lds (linear copy; swizzle baked
// into X). c_pool/bias prefetched into regs before the MFMA loop.
__global__ __launch_bounds__(512, 3)
void gemm_lstm_k(const float* __restrict__ c_pool, const float* __restrict__ bias,
                 const u16* __restrict__ Wbf, const u16* __restrict__ X,
                 const int4* __restrict__ meta, const int* __restrict__ hdr,
                 float* __restrict__ out) {
    __shared__ u16 sX[RT * KP];          // 40960 B, linear (swizzle pre-baked)
    __shared__ int4 sMeta[RT];

    const int bx  = blockIdx.x;
    const int tid = threadIdx.x;

    // stage X tile: 5 x 8KB global_load_lds (16B/lane), linear
    {
        const char* src = (const char*)X + (size_t)bx * (RT * KP * 2) + tid * 16;
        char* dst = (char*)sX + tid * 16;
        #pragma unroll
        for (int i = 0; i < 5; ++i)
            gld16(src + i * 8192, dst + i * 8192);
    }
    if (tid < RT) sMeta[tid] = meta[(size_t)bx * RT + tid];

    // type of this tile (uniform)
    int k = 0;
    #pragma unroll
    for (int j = 0; j < 7; ++j) k += (bx >= hdr[17 + j]);

    __syncthreads();   // drains vmcnt (global_load_lds) + lgkm

    const int wc = tid >> 6, lane = tid & 63;
    const int lo = lane & 15, hi = lane >> 4;
    const int hcol = wc * 16 + lo;

    // prefetch c_pool + bias (hides HBM latency under the MFMA loop)
    float cpl[16], cpr[16];
    #pragma unroll
    for (int m = 0; m < 4; ++m)
        #pragma unroll
        for (int jj = 0; jj < 4; ++jj) {
            int4 mt = sMeta[m * 16 + hi * 4 + jj];
            cpl[m * 4 + jj] = c_pool[(size_t)mt.y * HV + hcol];
            cpr[m * 4 + jj] = c_pool[(size_t)mt.z * HV + hcol];
        }
    float bb[5];
    #pragma unroll
    for (int g = 0; g < 5; ++g) bb[g] = bias[k * OO + g * 128 + hcol];

    // MFMA main loop
    f32x4 acc[5][4];
    #pragma unroll
    for (int g = 0; g < 5; ++g)
        #pragma unroll
        for (int m = 0; m < 4; ++m)
            acc[g][m] = (f32x4){0.f, 0.f, 0.f, 0.f};

    const u16* __restrict__ wbase = Wbf + (size_t)k * (OO * KP);
    int wo[5];
    #pragma unroll
    for (int g = 0; g < 5; ++g)
        wo[g] = (g * 128 + wc * 16 + lo) * KP + hi * 8;

    const char* sXb = (const char*)sX;
    const int rowbase = lo * 640;             // byte offset of row lo
    const int swzl = (lo & 7) << 4;           // same XOR the writer used

    #pragma unroll
    for (int kk = 0; kk < 10; ++kk) {
        const int kb = kk * 32;
        int a_off = rowbase + ((kk * 64 + hi * 16) ^ swzl);
        short8v a0 = *(const short8v*)(sXb + a_off);
        short8v a1 = *(const short8v*)(sXb + a_off + 10240);
        short8v a2 = *(const short8v*)(sXb + a_off + 20480);
        short8v a3 = *(const short8v*)(sXb + a_off + 30720);
        #pragma unroll
        for (int g = 0; g < 5; ++g) {
            short8v bf = *(const short8v*)(wbase + wo[g] + kb);
            acc[g][0] = __builtin_amdgcn_mfma_f32_16x16x32_bf16(a0, bf, acc[g][0], 0, 0, 0);
            acc[g][1] = __builtin_amdgcn_mfma_f32_16x16x32_bf16(a1, bf, acc[g][1], 0, 0, 0);
            acc[g][2] = __builtin_amdgcn_mfma_f32_16x16x32_bf16(a2, bf, acc[g][2], 0, 0, 0);
            acc[g][3] = __builtin_amdgcn_mfma_f32_16x16x32_bf16(a3, bf, acc[g][3], 0, 0, 0);
        }
    }

    // fused LSTM epilogue
    #pragma unroll
    for (int m = 0; m < 4; ++m) {
        #pragma unroll
        for (int jj = 0; jj < 4; ++jj) {
            int node = sMeta[m * 16 + hi * 4 + jj].x;
            if (node < 0) continue;
            float cl = cpl[m * 4 + jj], cr = cpr[m * 4 + jj];
            float gi  = acc[0][m][jj] + bb[0];
            float gfl = acc[1][m][jj] + bb[1];
            float gfr = acc[2][m][jj] + bb[2];
            float gu  = acc[3][m][jj] + bb[3];
            float go  = acc[4][m][jj] + bb[4];
            float cc = sigf(gi) * tanhfast(gu) + sigf(gfl) * cl + sigf(gfr) * cr;
            float hh = sigf(go) * tanhfast(cc);
            float* orow = out + (size_t)node * (2 * HV);
            orow[hcol]      = hh;
            orow[HV + hcol] = cc;
        }
    }
}

extern "C" void kernel_launch(void* const* d_in, const int* in_sizes, int n_in,
                              void* d_out, int out_size, void* d_ws, size_t ws_size,
                              hipStream_t stream) {
    const float* h_pool      = (const float*)d_in[0];
    const float* c_pool      = (const float*)d_in[1];
    const float* t_pool      = (const float*)d_in[2];
    const int*   child_idx   = (const int*)d_in[3];
    const int*   parent_type = (const int*)d_in[4];
    const float* W           = (const float*)d_in[5];
    const float* bias        = (const float*)d_in[6];
    float* out = (float*)d_out;

    const int N = in_sizes[3] / 2;
    const int maxblk = (N + RT - 1) / RT + KN;    // upper bound on row-tiles
    const int totrows = maxblk * RT;              // == N + KN*RT when N%RT==0

    char* ws = (char*)d_ws;
    size_t off = 0;
    int* hdr = (int*)ws;                         off += 1024;
    int* idxbuf = (int*)(ws + off);              off += (((size_t)totrows * 4 + 255) / 256) * 256;
    int4* meta = (int4*)(ws + off);              off += (size_t)totrows * 16;
    u16* Wbf = (u16*)(ws + off);                 off += (size_t)KN * OO * KP * 2;
    u16* X = (u16*)(ws + off);                   off += (size_t)totrows * KP * 2;

    hipMemsetAsync(hdr, 0, 1024, stream);
    hipMemsetAsync(idxbuf, 0xFF, (size_t)totrows * 4, stream);

    int nb = (N + 255) / 256;
    hist_k<<<nb, 256, 0, stream>>>(parent_type, hdr, N);
    prefix_k<<<1, 64, 0, stream>>>(hdr);
    scatter_k<<<nb, 256, 0, stream>>>(parent_type, hdr, idxbuf, N);
    wconv_k<<<dim3((OO * KP + 255) / 256, KN), 256, 0, stream>>>(W, Wbf);
    buildx_k<<<maxblk, 512, 0, stream>>>(h_pool, t_pool, child_idx, idxbuf, X, meta, totrows);
    gemm_lstm_k<<<maxblk, 512, 0, stream>>>(c_pool, bias, Wbf, X, meta, hdr, out);
}